// Round 11
// baseline (1511.386 us; speedup 1.0000x reference)
//
#include <hip/hip_runtime.h>
#include <hip/hip_fp16.h>
#include <stdint.h>

// TBRNN: x_{t+1} = x + 0.05*n_t + 0.2*(-x + rec(r) + inp_t), r = tanh(x)
// rec[b,i] = sum_{j,k} r[b,j] * w_hh[i,j,k] * r[b,k];  B=16, T=512, I=8, H=256
//
// Round 16 = round 15 (1262us) + ONE mechanism: 2-DEEP PIPELINED POLLS,
// CHECK-OLDER-SET (halves the IC sampling period, same data age):
//   fresh loop: detect = (RTT-RTT/2) + cadence/2 = 400+435 = ~835cyc
//   2-deep:     samples every ~RTT/2=400cyc     = 400+200 = ~600cyc
// r13 ran this structure but with wave0 (publisher) polling -- its sc1 store
// sat in the poll vmcnt domain (the real poison). Since r14 wave0 never
// polls; this is the clean re-run of the mechanism.
//  - wave1: 2 sets x 4 loads, vmcnt(4), per-pair retire inside loop.
//  - waves 2-3: 2 sets x 2 loads, vmcnt(2), single line per lane.
//  - no inner sleep (vmcnt self-paces at ~RTT/2); initial sleep(8) kept.
//  - register liveness: drain vmcnt(0) with all sets pinned before reuse.
// Diagnostic: FETCH should RISE ~2x poll-rate signature; dur should fall.

#define NOISE_STD 0.05f
#define TAU 0.2f

typedef _Float16 f16x8 __attribute__((ext_vector_type(8)));
typedef float f32x4 __attribute__((ext_vector_type(4)));
typedef unsigned int u32x4 __attribute__((ext_vector_type(4)));

__device__ __forceinline__ float fast_tanh(float x){
  float e = __expf(2.f*x);       // inf/0 at extremes -> exact +-1 below
  return 1.f - 2.f*__builtin_amdgcn_rcpf(e + 1.f);
}

// LDS-only block barrier: does NOT drain vmcnt (global stores stay in flight).
__device__ __forceinline__ void block_sync_lds(){
  asm volatile("s_waitcnt lgkmcnt(0)\n\ts_barrier" ::: "memory");
}

__device__ __forceinline__ unsigned pkmax_u16(unsigned a, unsigned b){
  unsigned d;
  asm("v_pk_max_u16 %0, %1, %2" : "=v"(d) : "v"(a), "v"(b));
  return d;
}

// true iff any u16 half of the 32B pair is the 0xFFFF sentinel.
// Exact: 0xFFFF is the u16 max, so any(half==FFFF) <=> pk-max column == FFFF.
__device__ __forceinline__ bool pair_bad(u32x4 a, u32x4 b){
  unsigned m = pkmax_u16(pkmax_u16(pkmax_u16(a.x, a.y), pkmax_u16(a.z, a.w)),
                         pkmax_u16(pkmax_u16(b.x, b.y), pkmax_u16(b.z, b.w)));
  return ((m & 0xFFFFu) == 0xFFFFu) || ((m >> 16) == 0xFFFFu);
}

// sum across each 16-lane row via DPP row_ror 1,2,4,8 (VALU-only, no LDS pipe)
__device__ __forceinline__ float row16_sum(float v){
  float s = v; int t;
  t = __builtin_amdgcn_update_dpp(__float_as_int(s), __float_as_int(s), 0x121, 0xF, 0xF, false); s += __int_as_float(t);
  t = __builtin_amdgcn_update_dpp(__float_as_int(s), __float_as_int(s), 0x122, 0xF, 0xF, false); s += __int_as_float(t);
  t = __builtin_amdgcn_update_dpp(__float_as_int(s), __float_as_int(s), 0x124, 0xF, 0xF, false); s += __int_as_float(t);
  t = __builtin_amdgcn_update_dpp(__float_as_int(s), __float_as_int(s), 0x128, 0xF, 0xF, false); s += __int_as_float(t);
  return s;
}

__device__ __forceinline__ unsigned pack2h(float a, float b){
  return (unsigned)__half_as_ushort(__float2half(a)) |
         ((unsigned)__half_as_ushort(__float2half(b)) << 16);
}

// ---- fused prep: pre2 + swizzled W (fp16) + rG sentinel fill, one launch ----
// pre2[h][t][b] = NOISE_STD*noise[t][b][h] + TAU*(u@w_in^T + b_in)[b][h]
// wsw uint4 index = ((i*4 + wv)*32 + jtl*8 + ks)*64 + lane, 8 halves each:
//   j = (wv*4+jtl)*16 + (lane&15), k = ks*32 + (lane>>4)*8 + e
__global__ void prep_kernel(const float* __restrict__ u, const float* __restrict__ noise,
                            const float* __restrict__ w_in_w, const float* __restrict__ w_in_b,
                            const float* __restrict__ w_hh,
                            float* __restrict__ pre2, __half* __restrict__ wsw,
                            uint4* __restrict__ rG4, int sent_u4){
  int F = blockIdx.x*256 + threadIdx.x;          // < 2097152
  // --- pre2 element, enumerated [t][h][b] ---
  {
    int b = F & 15; int h = (F>>4) & 255; int t = F >> 12;
    const float* up = u + (b*512 + t)*8;
    const float* wp = w_in_w + h*8;
    float s = w_in_b[h];
    #pragma unroll
    for (int i2 = 0; i2 < 8; ++i2) s += up[i2]*wp[i2];
    pre2[h*8192 + t*16 + b] = NOISE_STD*noise[t*4096 + b*256 + h] + TAU*s;
  }
  // --- one wsw uint4 (8 consecutive halves, same (lane,ks,jtl,wv,i)) ---
  {
    int lane = F & 63, ks = (F>>6)&7, jtl = (F>>9)&3, wv = (F>>11)&3, i = F>>13;
    int j = (wv*4 + jtl)*16 + (lane & 15);
    int kb = ks*32 + (lane>>4)*8;
    const float4* w4 = (const float4*)(w_hh + i*65536 + j*256 + kb);
    float4 a0 = w4[0], a1 = w4[1];
    uint4 o;
    o.x = pack2h(a0.x, a0.y); o.y = pack2h(a0.z, a0.w);
    o.z = pack2h(a1.x, a1.y); o.w = pack2h(a1.z, a1.w);
    ((uint4*)wsw)[F] = o;
  }
  // --- sentinel fill: rG region (LS*16384 uint4s) ---
  if (F < sent_u4){
    uint4 s4; s4.x = s4.y = s4.z = s4.w = 0xFFFFFFFFu;
    rG4[F] = s4;
  }
}

// ---- persistent recurrence kernel: 256 blocks x 256 threads, cooperative ----
__global__ void __launch_bounds__(256, 1) rnn_kernel(
    const float* __restrict__ x0, const float* __restrict__ pre2, const __half* __restrict__ wsw,
    __half* rG, float* __restrict__ traj, float* __restrict__ xlast, int LS)
{
  __shared__ alignas(16) unsigned short r_lds[16*264];  // r[b][k] fp16 bits, stride 264
  __shared__ alignas(16) unsigned short rT[256*20];     // r[k][b] fp16 bits, stride 20
  __shared__ alignas(16) float pre_lds[8192];           // pre2 slice [t][b_own]
  __shared__ alignas(16) float red[64];                 // [b][wv]

  const int tid = threadIdx.x;
  const int bid = blockIdx.x;                      // = i
  const int wv = tid >> 6, lane = tid & 63;
  const int q = lane >> 4, col = lane & 15;

  // owner/publisher wave wins issue arbitration (publish + own-line scatter)
  if (wv == 0) __builtin_amdgcn_s_setprio(1);

  // scatter a detected 32B line into both LDS copies
  auto scat = [&](int li, u32x4 d0, u32x4 d1){
    union { u32x4 v[2]; unsigned short h[16]; } U; U.v[0] = d0; U.v[1] = d1;
    #pragma unroll
    for (int b = 0; b < 16; ++b) r_lds[b*264 + li] = U.h[b];
    unsigned long long* rp = (unsigned long long*)&rT[li*20];
    rp[0] = ((unsigned long long)d0.y << 32) | d0.x;
    rp[1] = ((unsigned long long)d0.w << 32) | d0.z;
    rp[2] = ((unsigned long long)d1.y << 32) | d1.x;
    rp[3] = ((unsigned long long)d1.w << 32) | d1.z;
  };

  // ---- load W[i] fragments into registers once (32KB per wave) ----
  uint4 wreg[4][8];
  {
    const uint4* gw = (const uint4*)wsw + (size_t)(bid*4 + wv)*32*64 + lane;
    #pragma unroll
    for (int jtl = 0; jtl < 4; ++jtl)
      #pragma unroll
      for (int ks = 0; ks < 8; ++ks)
        wreg[jtl][ks] = gw[(jtl*8 + ks)*64];
  }

  // ---- pre slice (512 steps x 16 b = 32KB) -> LDS, fully coalesced ----
  {
    const float4* ps = (const float4*)(pre2 + bid*8192);
    float4* pl = (float4*)pre_lds;
    #pragma unroll
    for (int c = 0; c < 8; ++c) pl[c*256 + tid] = ps[c*256 + tid];
  }

  // ---- init: x slice in registers (lanes 0..15), r_0 in both LDS copies ----
  float xreg = 0.f;
  if (tid < 16) xreg = x0[tid*256 + bid];
  #pragma unroll
  for (int c = 0; c < 16; ++c){
    unsigned short rv = __half_as_ushort(__float2half(fast_tanh(x0[c*256 + tid])));
    r_lds[c*264 + tid] = rv;          // r[b=c][k=tid]
    rT[tid*20 + c]     = rv;          // r[k=tid][b=c]
  }
  __syncthreads();

  #pragma unroll 1
  for (int t = 0; t < 512; ++t){
    // prefetch the pre term for this step's publish (hidden under MFMA)
    float prev = 0.f;
    if (tid < 16) prev = pre_lds[t*16 + tid];

    // ---- stage 1: tmp[b][j] = sum_k W[i][j][k] r[b][k]  (all waves) ----
    f32x4 acc[4] = {{0.f,0.f,0.f,0.f},{0.f,0.f,0.f,0.f},{0.f,0.f,0.f,0.f},{0.f,0.f,0.f,0.f}};
    #pragma unroll
    for (int ks = 0; ks < 8; ++ks){
      f16x8 A = *(const f16x8*)(r_lds + col*264 + ks*32 + q*8);   // A[b=col][k-frag]
      #pragma unroll
      for (int jtl = 0; jtl < 4; ++jtl){
        union { uint4 u; f16x8 v; } wu; wu.u = wreg[jtl][ks];
        acc[jtl] = __builtin_amdgcn_mfma_f32_16x16x32_f16(A, wu.v, acc[jtl], 0, 0, 0);
      }
    }

    // ---- stage 2: rec[b] partial = sum_j r[b][j]*tmp[b][j] ----
    // D layout: col(j) = lane&15, row(b) = q*4 + reg.  r[b][j] from rT: one b64/jtl.
    float s[4] = {0.f, 0.f, 0.f, 0.f};
    #pragma unroll
    for (int jtl = 0; jtl < 4; ++jtl){
      int j = (wv*4 + jtl)*16 + col;
      unsigned long long rr = *(const unsigned long long*)&rT[j*20 + q*4];
      unsigned lo = (unsigned)rr, hi = (unsigned)(rr >> 32);
      s[0] += acc[jtl][0] * __half2float(__ushort_as_half((unsigned short)(lo & 0xFFFFu)));
      s[1] += acc[jtl][1] * __half2float(__ushort_as_half((unsigned short)(lo >> 16)));
      s[2] += acc[jtl][2] * __half2float(__ushort_as_half((unsigned short)(hi & 0xFFFFu)));
      s[3] += acc[jtl][3] * __half2float(__ushort_as_half((unsigned short)(hi >> 16)));
    }
    #pragma unroll
    for (int reg = 0; reg < 4; ++reg) s[reg] = row16_sum(s[reg]);
    if (col == 0){
      #pragma unroll
      for (int reg = 0; reg < 4; ++reg) red[(q*4 + reg)*4 + wv] = s[reg];
    }
    block_sync_lds();

    // ---- wave0 owners: update x, publish r fp16 (own padded line, sc1) ----
    if (tid < 16){
      float4 rr4 = *(const float4*)&red[tid*4];
      float rec = rr4.x + rr4.y + rr4.z + rr4.w;
      float xn = xreg + TAU*(rec - xreg) + prev;
      xreg = xn;
      unsigned rv = (unsigned)__half_as_ushort(__float2half(fast_tanh(xn)));
      __half* dst = rG + ((size_t)t*256 + bid)*LS + tid;
      asm volatile("global_store_short %0, %1, off sc1"
                   :: "v"(dst), "v"(rv) : "memory");
      traj[(size_t)tid*131072 + t*256 + bid] = xn;   // fp32, fire-and-forget
    }

    // ---- wave1: lines 0..127, 2-deep pipelined pair loop (check older) ----
    if (wv == 1 && t < 511){
      const int i0 = 2*lane, i1 = 2*lane + 1;
      const __half* cp0 = rG + ((size_t)t*256 + i0)*LS;   // 128B line, 32B used
      const __half* cp1 = cp0 + LS;
      u32x4 a0, a1, a2, a3, b0, b1, b2, b3;
      bool needL = true, needH = true;
      __builtin_amdgcn_s_sleep(8);                  // align first check with arrival
      asm volatile("global_load_dwordx4 %0, %4, off sc0 sc1\n\t"
                   "global_load_dwordx4 %1, %4, off offset:16 sc0 sc1\n\t"
                   "global_load_dwordx4 %2, %5, off sc0 sc1\n\t"
                   "global_load_dwordx4 %3, %5, off offset:16 sc0 sc1"
                   : "=&v"(a0), "=&v"(a1), "=&v"(a2), "=&v"(a3)
                   : "v"(cp0), "v"(cp1) : "memory");
      for (;;){
        asm volatile("global_load_dwordx4 %0, %4, off sc0 sc1\n\t"
                     "global_load_dwordx4 %1, %4, off offset:16 sc0 sc1\n\t"
                     "global_load_dwordx4 %2, %5, off sc0 sc1\n\t"
                     "global_load_dwordx4 %3, %5, off offset:16 sc0 sc1"
                     : "=&v"(b0), "=&v"(b1), "=&v"(b2), "=&v"(b3)
                     : "v"(cp0), "v"(cp1) : "memory");
        asm volatile("s_waitcnt vmcnt(4)" ::: "memory");
        __builtin_amdgcn_sched_barrier(0);
        if (needL && !pair_bad(a0, a1)){ scat(i0, a0, a1); needL = false; }
        if (needH && !pair_bad(a2, a3)){ scat(i1, a2, a3); needH = false; }
        if (!needL || !needH){ if (!needL && !needH) break; }
        asm volatile("global_load_dwordx4 %0, %4, off sc0 sc1\n\t"
                     "global_load_dwordx4 %1, %4, off offset:16 sc0 sc1\n\t"
                     "global_load_dwordx4 %2, %5, off sc0 sc1\n\t"
                     "global_load_dwordx4 %3, %5, off offset:16 sc0 sc1"
                     : "=&v"(a0), "=&v"(a1), "=&v"(a2), "=&v"(a3)
                     : "v"(cp0), "v"(cp1) : "memory");
        asm volatile("s_waitcnt vmcnt(4)" ::: "memory");
        __builtin_amdgcn_sched_barrier(0);
        if (needL && !pair_bad(b0, b1)){ scat(i0, b0, b1); needL = false; }
        if (needH && !pair_bad(b2, b3)){ scat(i1, b2, b3); needH = false; }
        if (!needL && !needH) break;
      }
      // drain all in-flight loads before these registers can be reused
      asm volatile("s_waitcnt vmcnt(0)"
                   :: "v"(a0), "v"(a1), "v"(a2), "v"(a3),
                      "v"(b0), "v"(b1), "v"(b2), "v"(b3) : "memory");
      __builtin_amdgcn_sched_barrier(0);
    }

    // ---- waves 2-3: one line per lane, 2-deep pipelined (check older) ----
    if (wv >= 2 && t < 511){
      const int li = tid;                           // tid 128..255 -> line 128..255
      const __half* cp = rG + ((size_t)t*256 + li)*LS;
      u32x4 a0, a1, b0, b1;
      bool useB = false;
      __builtin_amdgcn_s_sleep(8);                  // align first check with arrival
      asm volatile("global_load_dwordx4 %0, %2, off sc0 sc1\n\t"
                   "global_load_dwordx4 %1, %2, off offset:16 sc0 sc1"
                   : "=&v"(a0), "=&v"(a1) : "v"(cp) : "memory");
      for (;;){
        asm volatile("global_load_dwordx4 %0, %2, off sc0 sc1\n\t"
                     "global_load_dwordx4 %1, %2, off offset:16 sc0 sc1"
                     : "=&v"(b0), "=&v"(b1) : "v"(cp) : "memory");
        asm volatile("s_waitcnt vmcnt(2)" ::: "memory");
        __builtin_amdgcn_sched_barrier(0);
        if (!pair_bad(a0, a1)){ useB = false; break; }
        asm volatile("global_load_dwordx4 %0, %2, off sc0 sc1\n\t"
                     "global_load_dwordx4 %1, %2, off offset:16 sc0 sc1"
                     : "=&v"(a0), "=&v"(a1) : "v"(cp) : "memory");
        asm volatile("s_waitcnt vmcnt(2)" ::: "memory");
        __builtin_amdgcn_sched_barrier(0);
        if (!pair_bad(b0, b1)){ useB = true; break; }
      }
      // drain in-flight loads before register reuse; then scatter detected set
      asm volatile("s_waitcnt vmcnt(0)"
                   :: "v"(a0), "v"(a1), "v"(b0), "v"(b1) : "memory");
      __builtin_amdgcn_sched_barrier(0);
      u32x4 d0 = useB ? b0 : a0;
      u32x4 d1 = useB ? b1 : a1;
      scat(li, d0, d1);
    }
    block_sync_lds();
  }
  if (tid < 16) xlast[tid*256 + bid] = xreg;
}

// ---- out[b][t][o] = sum_h tanh(traj[b][t][h]) * w_out_w[o][h] + w_out_b[o] ----
__global__ void out_kernel(const float* __restrict__ traj, const float* __restrict__ w_out_w,
                           const float* __restrict__ w_out_b, float* __restrict__ out){
  __shared__ float wo[2048];
  int tid = threadIdx.x;
  #pragma unroll
  for (int c = 0; c < 8; ++c) wo[c*256 + tid] = w_out_w[c*256 + tid];
  __syncthreads();
  int wv = tid >> 6, lane = tid & 63;
  int p = blockIdx.x*4 + wv;                 // p = b*512 + t, < 8192
  float4 v = *(const float4*)&traj[(size_t)p*256 + lane*4];
  float th0 = fast_tanh(v.x), th1 = fast_tanh(v.y), th2 = fast_tanh(v.z), th3 = fast_tanh(v.w);
  #pragma unroll
  for (int o = 0; o < 8; ++o){
    const float* w = &wo[o*256 + lane*4];
    float s = th0*w[0] + th1*w[1] + th2*w[2] + th3*w[3];
    #pragma unroll
    for (int off = 32; off > 0; off >>= 1) s += __shfl_xor(s, off, 64);
    if (lane == 0) out[(size_t)p*8 + o] = s + w_out_b[o];
  }
}

extern "C" void kernel_launch(void* const* d_in, const int* in_sizes, int n_in,
                              void* d_out, int out_size, void* d_ws, size_t ws_size,
                              hipStream_t stream){
  const float* u       = (const float*)d_in[0];
  const float* x0      = (const float*)d_in[1];
  const float* noise   = (const float*)d_in[2];
  const float* w_hh    = (const float*)d_in[3];
  const float* w_in_w  = (const float*)d_in[4];
  const float* w_in_b  = (const float*)d_in[5];
  const float* w_out_w = (const float*)d_in[6];
  const float* w_out_b = (const float*)d_in[7];

  float* out   = (float*)d_out;          // [16][512][8]   = 65536
  float* xlast = out + 65536;            // [16][256]      = 4096
  float* traj  = xlast + 4096;           // [16][512][256] = 2097152

  // padded publish lines (128B/line) if workspace allows, else exact-r7 layout
  int LS = (ws_size >= (size_t)56*1024*1024) ? 64 : 16;
  size_t rg_bytes = (size_t)512*256*LS*2;              // 16 MiB (LS=64) / 4 MiB (LS=16)

  uint8_t* ws = (uint8_t*)d_ws;
  __half* rG   = (__half*)ws;                          // padded r-exchange
  float*  pre2 = (float*)(ws + rg_bytes);              // 8 MiB: [h][t][b]
  __half* wsw  = (__half*)(ws + rg_bytes + 8388608);   // 32 MiB swizzled W (fp16)

  prep_kernel<<<8192, 256, 0, stream>>>(u, noise, w_in_w, w_in_b, w_hh,
                                        pre2, wsw, (uint4*)rG, LS*16384);
  {
    void* args[] = {(void*)&x0, (void*)&pre2, (void*)&wsw,
                    (void*)&rG, (void*)&traj, (void*)&xlast, (void*)&LS};
    hipLaunchCooperativeKernel((const void*)rnn_kernel, dim3(256), dim3(256),
                               args, 0, stream);
  }
  out_kernel<<<2048, 256, 0, stream>>>(traj, w_out_w, w_out_b, out);
}

// Round 13
// 1421.643 us; speedup vs baseline: 1.0631x; 1.0631x over previous
//
#include <hip/hip_runtime.h>
#include <hip/hip_fp16.h>
#include <stdint.h>

// TBRNN: x_{t+1} = x + 0.05*n_t + 0.2*(-x + rec(r) + inp_t), r = tanh(x)
// rec[b,i] = sum_{j,k} r[b,j] * w_hh[i,j,k] * r[b,k];  B=16, T=512, I=8, H=256
//
// Round 18 = round 15 VERBATIM (best verified: rnn 1262us) + ONE knob:
//   miss-path sleep 1 -> 2 on all pollers (halves steady-state poll volume).
// Rationale: chip-wide poll request rate at r15 cadence ~145 req/cyc is at/
// above IC service throughput -> queueing inflates every RTT (incl. publish
// stores). r15's initial-sleep alignment (-73us) was also a volume cut.
// Cost: +32cyc avg detect quantization. Discriminates congestion-limited
// (wins) vs latency-limited (neutral -> r15 is the floor).
//
// CLOSED mechanism classes (ledger):
//  - pipelined/offset polls: r13 +150, r16 +141, r17 NaN. Only sleep-paced
//    fresh polls (issue -> vmcnt(0) -> verify) are safe+fast on this fabric.
//  - added serial hops (probe-verify r11, leader-bundle r12): +290 each.
//  - nt / always-miss polling (r8): +1700.
//  - publisher wave must never poll (r13): its sc1 store sits in the poll
//    vmcnt domain.

#define NOISE_STD 0.05f
#define TAU 0.2f

typedef _Float16 f16x8 __attribute__((ext_vector_type(8)));
typedef float f32x4 __attribute__((ext_vector_type(4)));
typedef unsigned int u32x4 __attribute__((ext_vector_type(4)));

__device__ __forceinline__ float fast_tanh(float x){
  float e = __expf(2.f*x);       // inf/0 at extremes -> exact +-1 below
  return 1.f - 2.f*__builtin_amdgcn_rcpf(e + 1.f);
}

// LDS-only block barrier: does NOT drain vmcnt (global stores stay in flight).
__device__ __forceinline__ void block_sync_lds(){
  asm volatile("s_waitcnt lgkmcnt(0)\n\ts_barrier" ::: "memory");
}

__device__ __forceinline__ unsigned pkmax_u16(unsigned a, unsigned b){
  unsigned d;
  asm("v_pk_max_u16 %0, %1, %2" : "=v"(d) : "v"(a), "v"(b));
  return d;
}

// true iff any u16 half of the 32B pair is the 0xFFFF sentinel.
// Exact: 0xFFFF is the u16 max, so any(half==FFFF) <=> pk-max column == FFFF.
__device__ __forceinline__ bool pair_bad(u32x4 a, u32x4 b){
  unsigned m = pkmax_u16(pkmax_u16(pkmax_u16(a.x, a.y), pkmax_u16(a.z, a.w)),
                         pkmax_u16(pkmax_u16(b.x, b.y), pkmax_u16(b.z, b.w)));
  return ((m & 0xFFFFu) == 0xFFFFu) || ((m >> 16) == 0xFFFFu);
}

// sum across each 16-lane row via DPP row_ror 1,2,4,8 (VALU-only, no LDS pipe)
__device__ __forceinline__ float row16_sum(float v){
  float s = v; int t;
  t = __builtin_amdgcn_update_dpp(__float_as_int(s), __float_as_int(s), 0x121, 0xF, 0xF, false); s += __int_as_float(t);
  t = __builtin_amdgcn_update_dpp(__float_as_int(s), __float_as_int(s), 0x122, 0xF, 0xF, false); s += __int_as_float(t);
  t = __builtin_amdgcn_update_dpp(__float_as_int(s), __float_as_int(s), 0x124, 0xF, 0xF, false); s += __int_as_float(t);
  t = __builtin_amdgcn_update_dpp(__float_as_int(s), __float_as_int(s), 0x128, 0xF, 0xF, false); s += __int_as_float(t);
  return s;
}

__device__ __forceinline__ unsigned pack2h(float a, float b){
  return (unsigned)__half_as_ushort(__float2half(a)) |
         ((unsigned)__half_as_ushort(__float2half(b)) << 16);
}

// ---- fused prep: pre2 + swizzled W (fp16) + rG sentinel fill, one launch ----
// pre2[h][t][b] = NOISE_STD*noise[t][b][h] + TAU*(u@w_in^T + b_in)[b][h]
// wsw uint4 index = ((i*4 + wv)*32 + jtl*8 + ks)*64 + lane, 8 halves each:
//   j = (wv*4+jtl)*16 + (lane&15), k = ks*32 + (lane>>4)*8 + e
__global__ void prep_kernel(const float* __restrict__ u, const float* __restrict__ noise,
                            const float* __restrict__ w_in_w, const float* __restrict__ w_in_b,
                            const float* __restrict__ w_hh,
                            float* __restrict__ pre2, __half* __restrict__ wsw,
                            uint4* __restrict__ rG4, int sent_u4){
  int F = blockIdx.x*256 + threadIdx.x;          // < 2097152
  // --- pre2 element, enumerated [t][h][b] ---
  {
    int b = F & 15; int h = (F>>4) & 255; int t = F >> 12;
    const float* up = u + (b*512 + t)*8;
    const float* wp = w_in_w + h*8;
    float s = w_in_b[h];
    #pragma unroll
    for (int i2 = 0; i2 < 8; ++i2) s += up[i2]*wp[i2];
    pre2[h*8192 + t*16 + b] = NOISE_STD*noise[t*4096 + b*256 + h] + TAU*s;
  }
  // --- one wsw uint4 (8 consecutive halves, same (lane,ks,jtl,wv,i)) ---
  {
    int lane = F & 63, ks = (F>>6)&7, jtl = (F>>9)&3, wv = (F>>11)&3, i = F>>13;
    int j = (wv*4 + jtl)*16 + (lane & 15);
    int kb = ks*32 + (lane>>4)*8;
    const float4* w4 = (const float4*)(w_hh + i*65536 + j*256 + kb);
    float4 a0 = w4[0], a1 = w4[1];
    uint4 o;
    o.x = pack2h(a0.x, a0.y); o.y = pack2h(a0.z, a0.w);
    o.z = pack2h(a1.x, a1.y); o.w = pack2h(a1.z, a1.w);
    ((uint4*)wsw)[F] = o;
  }
  // --- sentinel fill: rG region (LS*16384 uint4s) ---
  if (F < sent_u4){
    uint4 s4; s4.x = s4.y = s4.z = s4.w = 0xFFFFFFFFu;
    rG4[F] = s4;
  }
}

// ---- persistent recurrence kernel: 256 blocks x 256 threads, cooperative ----
__global__ void __launch_bounds__(256, 1) rnn_kernel(
    const float* __restrict__ x0, const float* __restrict__ pre2, const __half* __restrict__ wsw,
    __half* rG, float* __restrict__ traj, float* __restrict__ xlast, int LS)
{
  __shared__ alignas(16) unsigned short r_lds[16*264];  // r[b][k] fp16 bits, stride 264
  __shared__ alignas(16) unsigned short rT[256*20];     // r[k][b] fp16 bits, stride 20
  __shared__ alignas(16) float pre_lds[8192];           // pre2 slice [t][b_own]
  __shared__ alignas(16) float red[64];                 // [b][wv]

  const int tid = threadIdx.x;
  const int bid = blockIdx.x;                      // = i
  const int wv = tid >> 6, lane = tid & 63;
  const int q = lane >> 4, col = lane & 15;

  // owner/publisher wave wins issue arbitration (publish + own-line scatter)
  if (wv == 0) __builtin_amdgcn_s_setprio(1);

  // ---- load W[i] fragments into registers once (32KB per wave) ----
  uint4 wreg[4][8];
  {
    const uint4* gw = (const uint4*)wsw + (size_t)(bid*4 + wv)*32*64 + lane;
    #pragma unroll
    for (int jtl = 0; jtl < 4; ++jtl)
      #pragma unroll
      for (int ks = 0; ks < 8; ++ks)
        wreg[jtl][ks] = gw[(jtl*8 + ks)*64];
  }

  // ---- pre slice (512 steps x 16 b = 32KB) -> LDS, fully coalesced ----
  {
    const float4* ps = (const float4*)(pre2 + bid*8192);
    float4* pl = (float4*)pre_lds;
    #pragma unroll
    for (int c = 0; c < 8; ++c) pl[c*256 + tid] = ps[c*256 + tid];
  }

  // ---- init: x slice in registers (lanes 0..15), r_0 in both LDS copies ----
  float xreg = 0.f;
  if (tid < 16) xreg = x0[tid*256 + bid];
  #pragma unroll
  for (int c = 0; c < 16; ++c){
    unsigned short rv = __half_as_ushort(__float2half(fast_tanh(x0[c*256 + tid])));
    r_lds[c*264 + tid] = rv;          // r[b=c][k=tid]
    rT[tid*20 + c]     = rv;          // r[k=tid][b=c]
  }
  __syncthreads();

  #pragma unroll 1
  for (int t = 0; t < 512; ++t){
    // prefetch the pre term for this step's publish (hidden under MFMA; an
    // LDS read after the barrier sits on the publish critical path)
    float prev = 0.f;
    if (tid < 16) prev = pre_lds[t*16 + tid];

    // ---- stage 1: tmp[b][j] = sum_k W[i][j][k] r[b][k]  (all waves) ----
    f32x4 acc[4] = {{0.f,0.f,0.f,0.f},{0.f,0.f,0.f,0.f},{0.f,0.f,0.f,0.f},{0.f,0.f,0.f,0.f}};
    #pragma unroll
    for (int ks = 0; ks < 8; ++ks){
      f16x8 A = *(const f16x8*)(r_lds + col*264 + ks*32 + q*8);   // A[b=col][k-frag]
      #pragma unroll
      for (int jtl = 0; jtl < 4; ++jtl){
        union { uint4 u; f16x8 v; } wu; wu.u = wreg[jtl][ks];
        acc[jtl] = __builtin_amdgcn_mfma_f32_16x16x32_f16(A, wu.v, acc[jtl], 0, 0, 0);
      }
    }

    // ---- stage 2: rec[b] partial = sum_j r[b][j]*tmp[b][j] ----
    // D layout: col(j) = lane&15, row(b) = q*4 + reg.  r[b][j] from rT: one b64/jtl.
    float s[4] = {0.f, 0.f, 0.f, 0.f};
    #pragma unroll
    for (int jtl = 0; jtl < 4; ++jtl){
      int j = (wv*4 + jtl)*16 + col;
      unsigned long long rr = *(const unsigned long long*)&rT[j*20 + q*4];
      unsigned lo = (unsigned)rr, hi = (unsigned)(rr >> 32);
      s[0] += acc[jtl][0] * __half2float(__ushort_as_half((unsigned short)(lo & 0xFFFFu)));
      s[1] += acc[jtl][1] * __half2float(__ushort_as_half((unsigned short)(lo >> 16)));
      s[2] += acc[jtl][2] * __half2float(__ushort_as_half((unsigned short)(hi & 0xFFFFu)));
      s[3] += acc[jtl][3] * __half2float(__ushort_as_half((unsigned short)(hi >> 16)));
    }
    #pragma unroll
    for (int reg = 0; reg < 4; ++reg) s[reg] = row16_sum(s[reg]);
    if (col == 0){
      #pragma unroll
      for (int reg = 0; reg < 4; ++reg) red[(q*4 + reg)*4 + wv] = s[reg];
    }
    block_sync_lds();

    // ---- wave0 owners: update x, publish r fp16 (own padded line, sc1) ----
    if (tid < 16){
      float4 rr4 = *(const float4*)&red[tid*4];
      float rec = rr4.x + rr4.y + rr4.z + rr4.w;
      float xn = xreg + TAU*(rec - xreg) + prev;
      xreg = xn;
      unsigned rv = (unsigned)__half_as_ushort(__float2half(fast_tanh(xn)));
      __half* dst = rG + ((size_t)t*256 + bid)*LS + tid;
      asm volatile("global_store_short %0, %1, off sc1"
                   :: "v"(dst), "v"(rv) : "memory");
      traj[(size_t)tid*131072 + t*256 + bid] = xn;   // fp32, fire-and-forget
    }

    // ---- wave1: lines 0..127, staggered-pair fresh loop (p=lane) ----
    if (wv == 1 && t < 511){
      const int i0 = 2*lane, i1 = 2*lane + 1;
      const __half* cp0 = rG + ((size_t)t*256 + i0)*LS;   // 128B line, 32B used
      const __half* cp1 = cp0 + LS;
      u32x4 d0, d1, d2, d3;
      bool needL = true, needH = true;
      __builtin_amdgcn_s_sleep(8);                  // align first check with arrival
      for (;;){
        asm volatile("global_load_dwordx4 %0, %4, off sc0 sc1\n\t"
                     "global_load_dwordx4 %1, %4, off offset:16 sc0 sc1\n\t"
                     "global_load_dwordx4 %2, %5, off sc0 sc1\n\t"
                     "global_load_dwordx4 %3, %5, off offset:16 sc0 sc1"
                     : "=&v"(d0), "=&v"(d1), "=&v"(d2), "=&v"(d3)
                     : "v"(cp0), "v"(cp1) : "memory");
        asm volatile("s_waitcnt vmcnt(2)" ::: "memory");
        __builtin_amdgcn_sched_barrier(0);
        if (needL && !pair_bad(d0, d1)){
          union { u32x4 v[2]; unsigned short h[16]; } U; U.v[0] = d0; U.v[1] = d1;
          #pragma unroll
          for (int b = 0; b < 16; ++b) r_lds[b*264 + i0] = U.h[b];
          unsigned long long* rp = (unsigned long long*)&rT[i0*20];
          rp[0] = ((unsigned long long)d0.y << 32) | d0.x;
          rp[1] = ((unsigned long long)d0.w << 32) | d0.z;
          rp[2] = ((unsigned long long)d1.y << 32) | d1.x;
          rp[3] = ((unsigned long long)d1.w << 32) | d1.z;
          needL = false;
        }
        asm volatile("s_waitcnt vmcnt(0)" ::: "memory");
        __builtin_amdgcn_sched_barrier(0);
        if (needH && !pair_bad(d2, d3)){
          union { u32x4 v[2]; unsigned short h[16]; } U; U.v[0] = d2; U.v[1] = d3;
          #pragma unroll
          for (int b = 0; b < 16; ++b) r_lds[b*264 + i1] = U.h[b];
          unsigned long long* rp = (unsigned long long*)&rT[i1*20];
          rp[0] = ((unsigned long long)d2.y << 32) | d2.x;
          rp[1] = ((unsigned long long)d2.w << 32) | d2.z;
          rp[2] = ((unsigned long long)d3.y << 32) | d3.x;
          rp[3] = ((unsigned long long)d3.w << 32) | d3.z;
          needH = false;
        }
        if (!needL && !needH) break;
        __builtin_amdgcn_s_sleep(2);              // halved steady-state volume
      }
    }

    // ---- waves 2-3: ONE line per lane (lines 128..255), fresh sweeps ----
    if (wv >= 2 && t < 511){
      const int li = tid;                           // tid 128..255 -> line 128..255
      const __half* cp = rG + ((size_t)t*256 + li)*LS;
      u32x4 d0, d1;
      __builtin_amdgcn_s_sleep(8);                  // align first check with arrival
      for (;;){
        asm volatile("global_load_dwordx4 %0, %2, off sc0 sc1\n\t"
                     "global_load_dwordx4 %1, %2, off offset:16 sc0 sc1"
                     : "=&v"(d0), "=&v"(d1) : "v"(cp) : "memory");
        asm volatile("s_waitcnt vmcnt(0)" ::: "memory");
        __builtin_amdgcn_sched_barrier(0);
        if (!pair_bad(d0, d1)) break;
        __builtin_amdgcn_s_sleep(2);              // halved steady-state volume
      }
      union { u32x4 v[2]; unsigned short h[16]; } U; U.v[0] = d0; U.v[1] = d1;
      #pragma unroll
      for (int b = 0; b < 16; ++b) r_lds[b*264 + li] = U.h[b];
      unsigned long long* rp = (unsigned long long*)&rT[li*20];
      rp[0] = ((unsigned long long)d0.y << 32) | d0.x;
      rp[1] = ((unsigned long long)d0.w << 32) | d0.z;
      rp[2] = ((unsigned long long)d1.y << 32) | d1.x;
      rp[3] = ((unsigned long long)d1.w << 32) | d1.z;
    }
    block_sync_lds();
  }
  if (tid < 16) xlast[tid*256 + bid] = xreg;
}

// ---- out[b][t][o] = sum_h tanh(traj[b][t][h]) * w_out_w[o][h] + w_out_b[o] ----
__global__ void out_kernel(const float* __restrict__ traj, const float* __restrict__ w_out_w,
                           const float* __restrict__ w_out_b, float* __restrict__ out){
  __shared__ float wo[2048];
  int tid = threadIdx.x;
  #pragma unroll
  for (int c = 0; c < 8; ++c) wo[c*256 + tid] = w_out_w[c*256 + tid];
  __syncthreads();
  int wv = tid >> 6, lane = tid & 63;
  int p = blockIdx.x*4 + wv;                 // p = b*512 + t, < 8192
  float4 v = *(const float4*)&traj[(size_t)p*256 + lane*4];
  float th0 = fast_tanh(v.x), th1 = fast_tanh(v.y), th2 = fast_tanh(v.z), th3 = fast_tanh(v.w);
  #pragma unroll
  for (int o = 0; o < 8; ++o){
    const float* w = &wo[o*256 + lane*4];
    float s = th0*w[0] + th1*w[1] + th2*w[2] + th3*w[3];
    #pragma unroll
    for (int off = 32; off > 0; off >>= 1) s += __shfl_xor(s, off, 64);
    if (lane == 0) out[(size_t)p*8 + o] = s + w_out_b[o];
  }
}

extern "C" void kernel_launch(void* const* d_in, const int* in_sizes, int n_in,
                              void* d_out, int out_size, void* d_ws, size_t ws_size,
                              hipStream_t stream){
  const float* u       = (const float*)d_in[0];
  const float* x0      = (const float*)d_in[1];
  const float* noise   = (const float*)d_in[2];
  const float* w_hh    = (const float*)d_in[3];
  const float* w_in_w  = (const float*)d_in[4];
  const float* w_in_b  = (const float*)d_in[5];
  const float* w_out_w = (const float*)d_in[6];
  const float* w_out_b = (const float*)d_in[7];

  float* out   = (float*)d_out;          // [16][512][8]   = 65536
  float* xlast = out + 65536;            // [16][256]      = 4096
  float* traj  = xlast + 4096;           // [16][512][256] = 2097152

  // padded publish lines (128B/line) if workspace allows, else exact-r7 layout
  int LS = (ws_size >= (size_t)56*1024*1024) ? 64 : 16;
  size_t rg_bytes = (size_t)512*256*LS*2;              // 16 MiB (LS=64) / 4 MiB (LS=16)

  uint8_t* ws = (uint8_t*)d_ws;
  __half* rG   = (__half*)ws;                          // padded r-exchange
  float*  pre2 = (float*)(ws + rg_bytes);              // 8 MiB: [h][t][b]
  __half* wsw  = (__half*)(ws + rg_bytes + 8388608);   // 32 MiB swizzled W (fp16)

  prep_kernel<<<8192, 256, 0, stream>>>(u, noise, w_in_w, w_in_b, w_hh,
                                        pre2, wsw, (uint4*)rG, LS*16384);
  {
    void* args[] = {(void*)&x0, (void*)&pre2, (void*)&wsw,
                    (void*)&rG, (void*)&traj, (void*)&xlast, (void*)&LS};
    hipLaunchCooperativeKernel((const void*)rnn_kernel, dim3(256), dim3(256),
                               args, 0, stream);
  }
  out_kernel<<<2048, 256, 0, stream>>>(traj, w_out_w, w_out_b, out);
}

// Round 14
// 1292.462 us; speedup vs baseline: 1.1694x; 1.0999x over previous
//
#include <hip/hip_runtime.h>
#include <hip/hip_fp16.h>
#include <stdint.h>

// TBRNN: x_{t+1} = x + 0.05*n_t + 0.2*(-x + rec(r) + inp_t), r = tanh(x)
// rec[b,i] = sum_{j,k} r[b,j] * w_hh[i,j,k] * r[b,k];  B=16, T=512, I=8, H=256
//
// Round 19 = round 15 VERBATIM (best verified: rnn 1262us) + ONE timing knob:
//   initial poll sleep 8 -> 12 (both poller sites); miss-path sleep back to 1.
// Completing the 1-D alignment curve: sleep4=1335, sleep8=1262, sleep12=?
// Mechanism: first check reflects IC state at ~(sleep+450)cyc post-barrier;
// publish lands ~1100-1200. sleep8's first sample (~960) misses for most
// lines -> full extra cadence. sleep12 samples ~1200 (on-model arrival).
// Zero correctness risk (pure timing). r18 answered the volume question:
// congestion REFUTED (halved volume = +19us), exchange is latency-limited.
//
// CLOSED mechanism classes (ledger):
//  - pipelined/offset polls: r13 +150, r16 +141, r17 NaN. Only sleep-paced
//    fresh polls (issue -> vmcnt(0)/staggered vmcnt -> verify) are safe+fast.
//  - added serial hops (probe-verify r11, leader-bundle r12): +290 each.
//  - nt / always-miss polling (r8): +1700. Volume throttling (r18): +19.
//  - publisher wave must never poll (r13): store sits in poll vmcnt domain.

#define NOISE_STD 0.05f
#define TAU 0.2f

typedef _Float16 f16x8 __attribute__((ext_vector_type(8)));
typedef float f32x4 __attribute__((ext_vector_type(4)));
typedef unsigned int u32x4 __attribute__((ext_vector_type(4)));

__device__ __forceinline__ float fast_tanh(float x){
  float e = __expf(2.f*x);       // inf/0 at extremes -> exact +-1 below
  return 1.f - 2.f*__builtin_amdgcn_rcpf(e + 1.f);
}

// LDS-only block barrier: does NOT drain vmcnt (global stores stay in flight).
__device__ __forceinline__ void block_sync_lds(){
  asm volatile("s_waitcnt lgkmcnt(0)\n\ts_barrier" ::: "memory");
}

__device__ __forceinline__ unsigned pkmax_u16(unsigned a, unsigned b){
  unsigned d;
  asm("v_pk_max_u16 %0, %1, %2" : "=v"(d) : "v"(a), "v"(b));
  return d;
}

// true iff any u16 half of the 32B pair is the 0xFFFF sentinel.
// Exact: 0xFFFF is the u16 max, so any(half==FFFF) <=> pk-max column == FFFF.
__device__ __forceinline__ bool pair_bad(u32x4 a, u32x4 b){
  unsigned m = pkmax_u16(pkmax_u16(pkmax_u16(a.x, a.y), pkmax_u16(a.z, a.w)),
                         pkmax_u16(pkmax_u16(b.x, b.y), pkmax_u16(b.z, b.w)));
  return ((m & 0xFFFFu) == 0xFFFFu) || ((m >> 16) == 0xFFFFu);
}

// sum across each 16-lane row via DPP row_ror 1,2,4,8 (VALU-only, no LDS pipe)
__device__ __forceinline__ float row16_sum(float v){
  float s = v; int t;
  t = __builtin_amdgcn_update_dpp(__float_as_int(s), __float_as_int(s), 0x121, 0xF, 0xF, false); s += __int_as_float(t);
  t = __builtin_amdgcn_update_dpp(__float_as_int(s), __float_as_int(s), 0x122, 0xF, 0xF, false); s += __int_as_float(t);
  t = __builtin_amdgcn_update_dpp(__float_as_int(s), __float_as_int(s), 0x124, 0xF, 0xF, false); s += __int_as_float(t);
  t = __builtin_amdgcn_update_dpp(__float_as_int(s), __float_as_int(s), 0x128, 0xF, 0xF, false); s += __int_as_float(t);
  return s;
}

__device__ __forceinline__ unsigned pack2h(float a, float b){
  return (unsigned)__half_as_ushort(__float2half(a)) |
         ((unsigned)__half_as_ushort(__float2half(b)) << 16);
}

// ---- fused prep: pre2 + swizzled W (fp16) + rG sentinel fill, one launch ----
// pre2[h][t][b] = NOISE_STD*noise[t][b][h] + TAU*(u@w_in^T + b_in)[b][h]
// wsw uint4 index = ((i*4 + wv)*32 + jtl*8 + ks)*64 + lane, 8 halves each:
//   j = (wv*4+jtl)*16 + (lane&15), k = ks*32 + (lane>>4)*8 + e
__global__ void prep_kernel(const float* __restrict__ u, const float* __restrict__ noise,
                            const float* __restrict__ w_in_w, const float* __restrict__ w_in_b,
                            const float* __restrict__ w_hh,
                            float* __restrict__ pre2, __half* __restrict__ wsw,
                            uint4* __restrict__ rG4, int sent_u4){
  int F = blockIdx.x*256 + threadIdx.x;          // < 2097152
  // --- pre2 element, enumerated [t][h][b] ---
  {
    int b = F & 15; int h = (F>>4) & 255; int t = F >> 12;
    const float* up = u + (b*512 + t)*8;
    const float* wp = w_in_w + h*8;
    float s = w_in_b[h];
    #pragma unroll
    for (int i2 = 0; i2 < 8; ++i2) s += up[i2]*wp[i2];
    pre2[h*8192 + t*16 + b] = NOISE_STD*noise[t*4096 + b*256 + h] + TAU*s;
  }
  // --- one wsw uint4 (8 consecutive halves, same (lane,ks,jtl,wv,i)) ---
  {
    int lane = F & 63, ks = (F>>6)&7, jtl = (F>>9)&3, wv = (F>>11)&3, i = F>>13;
    int j = (wv*4 + jtl)*16 + (lane & 15);
    int kb = ks*32 + (lane>>4)*8;
    const float4* w4 = (const float4*)(w_hh + i*65536 + j*256 + kb);
    float4 a0 = w4[0], a1 = w4[1];
    uint4 o;
    o.x = pack2h(a0.x, a0.y); o.y = pack2h(a0.z, a0.w);
    o.z = pack2h(a1.x, a1.y); o.w = pack2h(a1.z, a1.w);
    ((uint4*)wsw)[F] = o;
  }
  // --- sentinel fill: rG region (LS*16384 uint4s) ---
  if (F < sent_u4){
    uint4 s4; s4.x = s4.y = s4.z = s4.w = 0xFFFFFFFFu;
    rG4[F] = s4;
  }
}

// ---- persistent recurrence kernel: 256 blocks x 256 threads, cooperative ----
__global__ void __launch_bounds__(256, 1) rnn_kernel(
    const float* __restrict__ x0, const float* __restrict__ pre2, const __half* __restrict__ wsw,
    __half* rG, float* __restrict__ traj, float* __restrict__ xlast, int LS)
{
  __shared__ alignas(16) unsigned short r_lds[16*264];  // r[b][k] fp16 bits, stride 264
  __shared__ alignas(16) unsigned short rT[256*20];     // r[k][b] fp16 bits, stride 20
  __shared__ alignas(16) float pre_lds[8192];           // pre2 slice [t][b_own]
  __shared__ alignas(16) float red[64];                 // [b][wv]

  const int tid = threadIdx.x;
  const int bid = blockIdx.x;                      // = i
  const int wv = tid >> 6, lane = tid & 63;
  const int q = lane >> 4, col = lane & 15;

  // owner/publisher wave wins issue arbitration (publish + own-line scatter)
  if (wv == 0) __builtin_amdgcn_s_setprio(1);

  // ---- load W[i] fragments into registers once (32KB per wave) ----
  uint4 wreg[4][8];
  {
    const uint4* gw = (const uint4*)wsw + (size_t)(bid*4 + wv)*32*64 + lane;
    #pragma unroll
    for (int jtl = 0; jtl < 4; ++jtl)
      #pragma unroll
      for (int ks = 0; ks < 8; ++ks)
        wreg[jtl][ks] = gw[(jtl*8 + ks)*64];
  }

  // ---- pre slice (512 steps x 16 b = 32KB) -> LDS, fully coalesced ----
  {
    const float4* ps = (const float4*)(pre2 + bid*8192);
    float4* pl = (float4*)pre_lds;
    #pragma unroll
    for (int c = 0; c < 8; ++c) pl[c*256 + tid] = ps[c*256 + tid];
  }

  // ---- init: x slice in registers (lanes 0..15), r_0 in both LDS copies ----
  float xreg = 0.f;
  if (tid < 16) xreg = x0[tid*256 + bid];
  #pragma unroll
  for (int c = 0; c < 16; ++c){
    unsigned short rv = __half_as_ushort(__float2half(fast_tanh(x0[c*256 + tid])));
    r_lds[c*264 + tid] = rv;          // r[b=c][k=tid]
    rT[tid*20 + c]     = rv;          // r[k=tid][b=c]
  }
  __syncthreads();

  #pragma unroll 1
  for (int t = 0; t < 512; ++t){
    // prefetch the pre term for this step's publish (hidden under MFMA; an
    // LDS read after the barrier sits on the publish critical path)
    float prev = 0.f;
    if (tid < 16) prev = pre_lds[t*16 + tid];

    // ---- stage 1: tmp[b][j] = sum_k W[i][j][k] r[b][k]  (all waves) ----
    f32x4 acc[4] = {{0.f,0.f,0.f,0.f},{0.f,0.f,0.f,0.f},{0.f,0.f,0.f,0.f},{0.f,0.f,0.f,0.f}};
    #pragma unroll
    for (int ks = 0; ks < 8; ++ks){
      f16x8 A = *(const f16x8*)(r_lds + col*264 + ks*32 + q*8);   // A[b=col][k-frag]
      #pragma unroll
      for (int jtl = 0; jtl < 4; ++jtl){
        union { uint4 u; f16x8 v; } wu; wu.u = wreg[jtl][ks];
        acc[jtl] = __builtin_amdgcn_mfma_f32_16x16x32_f16(A, wu.v, acc[jtl], 0, 0, 0);
      }
    }

    // ---- stage 2: rec[b] partial = sum_j r[b][j]*tmp[b][j] ----
    // D layout: col(j) = lane&15, row(b) = q*4 + reg.  r[b][j] from rT: one b64/jtl.
    float s[4] = {0.f, 0.f, 0.f, 0.f};
    #pragma unroll
    for (int jtl = 0; jtl < 4; ++jtl){
      int j = (wv*4 + jtl)*16 + col;
      unsigned long long rr = *(const unsigned long long*)&rT[j*20 + q*4];
      unsigned lo = (unsigned)rr, hi = (unsigned)(rr >> 32);
      s[0] += acc[jtl][0] * __half2float(__ushort_as_half((unsigned short)(lo & 0xFFFFu)));
      s[1] += acc[jtl][1] * __half2float(__ushort_as_half((unsigned short)(lo >> 16)));
      s[2] += acc[jtl][2] * __half2float(__ushort_as_half((unsigned short)(hi & 0xFFFFu)));
      s[3] += acc[jtl][3] * __half2float(__ushort_as_half((unsigned short)(hi >> 16)));
    }
    #pragma unroll
    for (int reg = 0; reg < 4; ++reg) s[reg] = row16_sum(s[reg]);
    if (col == 0){
      #pragma unroll
      for (int reg = 0; reg < 4; ++reg) red[(q*4 + reg)*4 + wv] = s[reg];
    }
    block_sync_lds();

    // ---- wave0 owners: update x, publish r fp16 (own padded line, sc1) ----
    if (tid < 16){
      float4 rr4 = *(const float4*)&red[tid*4];
      float rec = rr4.x + rr4.y + rr4.z + rr4.w;
      float xn = xreg + TAU*(rec - xreg) + prev;
      xreg = xn;
      unsigned rv = (unsigned)__half_as_ushort(__float2half(fast_tanh(xn)));
      __half* dst = rG + ((size_t)t*256 + bid)*LS + tid;
      asm volatile("global_store_short %0, %1, off sc1"
                   :: "v"(dst), "v"(rv) : "memory");
      traj[(size_t)tid*131072 + t*256 + bid] = xn;   // fp32, fire-and-forget
    }

    // ---- wave1: lines 0..127, staggered-pair fresh loop (p=lane) ----
    if (wv == 1 && t < 511){
      const int i0 = 2*lane, i1 = 2*lane + 1;
      const __half* cp0 = rG + ((size_t)t*256 + i0)*LS;   // 128B line, 32B used
      const __half* cp1 = cp0 + LS;
      u32x4 d0, d1, d2, d3;
      bool needL = true, needH = true;
      __builtin_amdgcn_s_sleep(12);                 // first sample ~= arrival time
      for (;;){
        asm volatile("global_load_dwordx4 %0, %4, off sc0 sc1\n\t"
                     "global_load_dwordx4 %1, %4, off offset:16 sc0 sc1\n\t"
                     "global_load_dwordx4 %2, %5, off sc0 sc1\n\t"
                     "global_load_dwordx4 %3, %5, off offset:16 sc0 sc1"
                     : "=&v"(d0), "=&v"(d1), "=&v"(d2), "=&v"(d3)
                     : "v"(cp0), "v"(cp1) : "memory");
        asm volatile("s_waitcnt vmcnt(2)" ::: "memory");
        __builtin_amdgcn_sched_barrier(0);
        if (needL && !pair_bad(d0, d1)){
          union { u32x4 v[2]; unsigned short h[16]; } U; U.v[0] = d0; U.v[1] = d1;
          #pragma unroll
          for (int b = 0; b < 16; ++b) r_lds[b*264 + i0] = U.h[b];
          unsigned long long* rp = (unsigned long long*)&rT[i0*20];
          rp[0] = ((unsigned long long)d0.y << 32) | d0.x;
          rp[1] = ((unsigned long long)d0.w << 32) | d0.z;
          rp[2] = ((unsigned long long)d1.y << 32) | d1.x;
          rp[3] = ((unsigned long long)d1.w << 32) | d1.z;
          needL = false;
        }
        asm volatile("s_waitcnt vmcnt(0)" ::: "memory");
        __builtin_amdgcn_sched_barrier(0);
        if (needH && !pair_bad(d2, d3)){
          union { u32x4 v[2]; unsigned short h[16]; } U; U.v[0] = d2; U.v[1] = d3;
          #pragma unroll
          for (int b = 0; b < 16; ++b) r_lds[b*264 + i1] = U.h[b];
          unsigned long long* rp = (unsigned long long*)&rT[i1*20];
          rp[0] = ((unsigned long long)d2.y << 32) | d2.x;
          rp[1] = ((unsigned long long)d2.w << 32) | d2.z;
          rp[2] = ((unsigned long long)d3.y << 32) | d3.x;
          rp[3] = ((unsigned long long)d3.w << 32) | d3.z;
          needH = false;
        }
        if (!needL && !needH) break;
        __builtin_amdgcn_s_sleep(1);
      }
    }

    // ---- waves 2-3: ONE line per lane (lines 128..255), fresh sweeps ----
    if (wv >= 2 && t < 511){
      const int li = tid;                           // tid 128..255 -> line 128..255
      const __half* cp = rG + ((size_t)t*256 + li)*LS;
      u32x4 d0, d1;
      __builtin_amdgcn_s_sleep(12);                 // first sample ~= arrival time
      for (;;){
        asm volatile("global_load_dwordx4 %0, %2, off sc0 sc1\n\t"
                     "global_load_dwordx4 %1, %2, off offset:16 sc0 sc1"
                     : "=&v"(d0), "=&v"(d1) : "v"(cp) : "memory");
        asm volatile("s_waitcnt vmcnt(0)" ::: "memory");
        __builtin_amdgcn_sched_barrier(0);
        if (!pair_bad(d0, d1)) break;
        __builtin_amdgcn_s_sleep(1);
      }
      union { u32x4 v[2]; unsigned short h[16]; } U; U.v[0] = d0; U.v[1] = d1;
      #pragma unroll
      for (int b = 0; b < 16; ++b) r_lds[b*264 + li] = U.h[b];
      unsigned long long* rp = (unsigned long long*)&rT[li*20];
      rp[0] = ((unsigned long long)d0.y << 32) | d0.x;
      rp[1] = ((unsigned long long)d0.w << 32) | d0.z;
      rp[2] = ((unsigned long long)d1.y << 32) | d1.x;
      rp[3] = ((unsigned long long)d1.w << 32) | d1.z;
    }
    block_sync_lds();
  }
  if (tid < 16) xlast[tid*256 + bid] = xreg;
}

// ---- out[b][t][o] = sum_h tanh(traj[b][t][h]) * w_out_w[o][h] + w_out_b[o] ----
__global__ void out_kernel(const float* __restrict__ traj, const float* __restrict__ w_out_w,
                           const float* __restrict__ w_out_b, float* __restrict__ out){
  __shared__ float wo[2048];
  int tid = threadIdx.x;
  #pragma unroll
  for (int c = 0; c < 8; ++c) wo[c*256 + tid] = w_out_w[c*256 + tid];
  __syncthreads();
  int wv = tid >> 6, lane = tid & 63;
  int p = blockIdx.x*4 + wv;                 // p = b*512 + t, < 8192
  float4 v = *(const float4*)&traj[(size_t)p*256 + lane*4];
  float th0 = fast_tanh(v.x), th1 = fast_tanh(v.y), th2 = fast_tanh(v.z), th3 = fast_tanh(v.w);
  #pragma unroll
  for (int o = 0; o < 8; ++o){
    const float* w = &wo[o*256 + lane*4];
    float s = th0*w[0] + th1*w[1] + th2*w[2] + th3*w[3];
    #pragma unroll
    for (int off = 32; off > 0; off >>= 1) s += __shfl_xor(s, off, 64);
    if (lane == 0) out[(size_t)p*8 + o] = s + w_out_b[o];
  }
}

extern "C" void kernel_launch(void* const* d_in, const int* in_sizes, int n_in,
                              void* d_out, int out_size, void* d_ws, size_t ws_size,
                              hipStream_t stream){
  const float* u       = (const float*)d_in[0];
  const float* x0      = (const float*)d_in[1];
  const float* noise   = (const float*)d_in[2];
  const float* w_hh    = (const float*)d_in[3];
  const float* w_in_w  = (const float*)d_in[4];
  const float* w_in_b  = (const float*)d_in[5];
  const float* w_out_w = (const float*)d_in[6];
  const float* w_out_b = (const float*)d_in[7];

  float* out   = (float*)d_out;          // [16][512][8]   = 65536
  float* xlast = out + 65536;            // [16][256]      = 4096
  float* traj  = xlast + 4096;           // [16][512][256] = 2097152

  // padded publish lines (128B/line) if workspace allows, else exact-r7 layout
  int LS = (ws_size >= (size_t)56*1024*1024) ? 64 : 16;
  size_t rg_bytes = (size_t)512*256*LS*2;              // 16 MiB (LS=64) / 4 MiB (LS=16)

  uint8_t* ws = (uint8_t*)d_ws;
  __half* rG   = (__half*)ws;                          // padded r-exchange
  float*  pre2 = (float*)(ws + rg_bytes);              // 8 MiB: [h][t][b]
  __half* wsw  = (__half*)(ws + rg_bytes + 8388608);   // 32 MiB swizzled W (fp16)

  prep_kernel<<<8192, 256, 0, stream>>>(u, noise, w_in_w, w_in_b, w_hh,
                                        pre2, wsw, (uint4*)rG, LS*16384);
  {
    void* args[] = {(void*)&x0, (void*)&pre2, (void*)&wsw,
                    (void*)&rG, (void*)&traj, (void*)&xlast, (void*)&LS};
    hipLaunchCooperativeKernel((const void*)rnn_kernel, dim3(256), dim3(256),
                               args, 0, stream);
  }
  out_kernel<<<2048, 256, 0, stream>>>(traj, w_out_w, w_out_b, out);
}